// Round 1
// baseline (646.468 us; speedup 1.0000x reference)
//
#include <hip/hip_runtime.h>

#define NN 10000
#define NE 400000
#define HD 128
#define NIN 6
#define EDIM 3
#define NL 4
#define LN_EPS 1e-5f

// ---------------- preprocessing: counts / scan / counting-sort ----------------

__global__ __launch_bounds__(256) void k_zero_counts(int* counts) {
    int i = blockIdx.x * 256 + threadIdx.x;
    if (i < NN) counts[i] = 0;
}

__global__ __launch_bounds__(256) void k_count(const int* __restrict__ tgt, int* __restrict__ counts) {
    int e = blockIdx.x * 256 + threadIdx.x;
    if (e < NE) atomicAdd(&counts[tgt[e]], 1);
}

__global__ __launch_bounds__(1024) void k_scan(const int* __restrict__ counts, int* __restrict__ offsets,
                                               int* __restrict__ cursor, float* __restrict__ inv,
                                               float* __restrict__ alpha) {
    __shared__ int buf[1024];
    int tid = threadIdx.x;
    int base = 0;
    for (int start = 0; start < NN; start += 1024) {
        int i = start + tid;
        int c = (i < NN) ? counts[i] : 0;
        buf[tid] = c;
        __syncthreads();
        for (int off = 1; off < 1024; off <<= 1) {
            int v = (tid >= off) ? buf[tid - off] : 0;
            __syncthreads();
            buf[tid] += v;
            __syncthreads();
        }
        if (i < NN) {
            int excl = base + buf[tid] - c;
            offsets[i] = excl;
            cursor[i] = excl;
            inv[i] = 1.0f / fmaxf((float)c, 1.0f);
            alpha[i] = (c > 0) ? 1.0f : 0.0f;
        }
        base += buf[1023];
        __syncthreads();
    }
    if (tid == 0) offsets[NN] = base;
}

__global__ __launch_bounds__(256) void k_scatter(const int* __restrict__ src, const int* __restrict__ tgt,
                                                 const float* __restrict__ ea, int* __restrict__ cursor,
                                                 int* __restrict__ ssrc, float4* __restrict__ sea) {
    int e = blockIdx.x * 256 + threadIdx.x;
    if (e >= NE) return;
    int t = tgt[e];
    int pos = atomicAdd(&cursor[t], 1);
    ssrc[pos] = src[e];
    sea[pos] = make_float4(ea[e * 3], ea[e * 3 + 1], ea[e * 3 + 2], 0.f);
}

// ---------------- weight prep: M2 = msg_w2 @ upd_w1[128:], c2 = msg_b2 @ upd_w1[128:] --------

__global__ __launch_bounds__(256) void k_prep_m2(const float* __restrict__ msg_w2, const float* __restrict__ upd_w1,
                                                 float* __restrict__ M2) {
    int idx = blockIdx.x * 256 + threadIdx.x;  // NL*HD*HD threads
    int l = idx >> 14;
    int rem = idx & 16383;
    int i = rem >> 7;
    int j = rem & 127;
    const float* W2 = msg_w2 + (size_t)l * HD * HD;
    const float* U1b = upd_w1 + (size_t)l * 2 * HD * HD + (size_t)HD * HD;  // rows 128..255
    float acc = 0.f;
    for (int t = 0; t < HD; ++t) acc += W2[i * HD + t] * U1b[t * HD + j];
    M2[idx] = acc;
}

__global__ __launch_bounds__(256) void k_prep_c2(const float* __restrict__ msg_b2, const float* __restrict__ upd_w1,
                                                 float* __restrict__ c2) {
    int idx = blockIdx.x * 256 + threadIdx.x;  // NL*HD
    if (idx >= NL * HD) return;
    int l = idx >> 7;
    int j = idx & 127;
    const float* U1b = upd_w1 + (size_t)l * 2 * HD * HD + (size_t)HD * HD;
    const float* b2 = msg_b2 + l * HD;
    float acc = 0.f;
    for (int t = 0; t < HD; ++t) acc += b2[t] * U1b[t * HD + j];
    c2[idx] = acc;
}

// ---------------- encoder: h = relu(x@W1+b1)@W2+b2 ----------------

__global__ __launch_bounds__(256) void k_encoder(const float* __restrict__ x, const float* __restrict__ w1,
                                                 const float* __restrict__ b1, const float* __restrict__ w2,
                                                 const float* __restrict__ b2, float* __restrict__ h) {
    __shared__ float tb[4][128];
    int tid = threadIdx.x, wid = tid >> 6, lane = tid & 63;
    int n = blockIdx.x * 4 + wid;
    int j = lane * 2;
    float xr[NIN];
#pragma unroll
    for (int k = 0; k < NIN; ++k) xr[k] = x[(size_t)n * NIN + k];
    float t0 = b1[j], t1 = b1[j + 1];
#pragma unroll
    for (int k = 0; k < NIN; ++k) {
        float2 w = *(const float2*)(w1 + k * HD + j);
        t0 += xr[k] * w.x;
        t1 += xr[k] * w.y;
    }
    tb[wid][j] = fmaxf(t0, 0.f);
    tb[wid][j + 1] = fmaxf(t1, 0.f);
    __syncthreads();
    float a0 = b2[j], a1 = b2[j + 1];
    for (int k = 0; k < HD; ++k) {
        float xx = tb[wid][k];
        float2 w = *(const float2*)(w2 + k * HD + j);
        a0 += xx * w.x;
        a1 += xx * w.y;
    }
    h[(size_t)n * HD + j] = a0;
    h[(size_t)n * HD + j + 1] = a1;
}

// ---------------- PQ = h @ [W1a | W1b]  (+ b1 folded into P half) ----------------

__global__ __launch_bounds__(256) void k_pq(const float* __restrict__ h, const float* __restrict__ w1,
                                            const float* __restrict__ b1, float* __restrict__ PQ) {
    __shared__ float atile[16][128];
    int tid = threadIdx.x;
    int row0 = blockIdx.x * 16;
    {
        const float4* s = (const float4*)(h + (size_t)row0 * HD);
        float4* d = (float4*)&atile[0][0];
        for (int i = tid; i < 16 * HD / 4; i += 256) d[i] = s[i];
    }
    __syncthreads();
    int wid = tid >> 6, lane = tid & 63;
    int j = lane * 4;  // 0..252 over 256 output cols
    const float* Bb = (j < HD) ? (w1 + j) : (w1 + (size_t)HD * HD + (j - HD));
    int r0 = wid * 4;
    float4 a0 = {0, 0, 0, 0}, a1 = {0, 0, 0, 0}, a2 = {0, 0, 0, 0}, a3 = {0, 0, 0, 0};
    for (int k = 0; k < HD; ++k) {
        float4 w = *(const float4*)(Bb + (size_t)k * HD);
        float x0 = atile[r0 + 0][k], x1 = atile[r0 + 1][k], x2 = atile[r0 + 2][k], x3 = atile[r0 + 3][k];
        a0.x += x0 * w.x; a0.y += x0 * w.y; a0.z += x0 * w.z; a0.w += x0 * w.w;
        a1.x += x1 * w.x; a1.y += x1 * w.y; a1.z += x1 * w.z; a1.w += x1 * w.w;
        a2.x += x2 * w.x; a2.y += x2 * w.y; a2.z += x2 * w.z; a2.w += x2 * w.w;
        a3.x += x3 * w.x; a3.y += x3 * w.y; a3.z += x3 * w.z; a3.w += x3 * w.w;
    }
    float4 bias = {0, 0, 0, 0};
    if (j < HD) bias = *(const float4*)(b1 + j);
    a0.x += bias.x; a0.y += bias.y; a0.z += bias.z; a0.w += bias.w;
    a1.x += bias.x; a1.y += bias.y; a1.z += bias.z; a1.w += bias.w;
    a2.x += bias.x; a2.y += bias.y; a2.z += bias.z; a2.w += bias.w;
    a3.x += bias.x; a3.y += bias.y; a3.z += bias.z; a3.w += bias.w;
    *(float4*)(PQ + (size_t)(row0 + r0 + 0) * 256 + j) = a0;
    *(float4*)(PQ + (size_t)(row0 + r0 + 1) * 256 + j) = a1;
    *(float4*)(PQ + (size_t)(row0 + r0 + 2) * 256 + j) = a2;
    *(float4*)(PQ + (size_t)(row0 + r0 + 3) * 256 + j) = a3;
}

// ---------------- edge phase: S[n] = inv[n] * sum_e relu(P[n] + Q[src] + ea@W1c) -------------
// One wave per node, CSR order (no atomics). 2x unroll to overlap gather latency.

__global__ __launch_bounds__(256) void k_edge(const float* __restrict__ PQ, const int* __restrict__ offsets,
                                              const int* __restrict__ ssrc, const float4* __restrict__ sea,
                                              const float* __restrict__ w1, const float* __restrict__ inv,
                                              float* __restrict__ S) {
    int n = (blockIdx.x * 256 + threadIdx.x) >> 6;
    int lane = threadIdx.x & 63;
    if (n >= NN) return;
    int j = lane * 2;
    float2 p = *(const float2*)(PQ + (size_t)n * 256 + j);
    const float* wc = w1 + (size_t)(2 * HD) * HD;
    float2 wc0 = *(const float2*)(wc + j);
    float2 wc1 = *(const float2*)(wc + HD + j);
    float2 wc2 = *(const float2*)(wc + 2 * HD + j);
    int beg = offsets[n], end = offsets[n + 1];
    float acc0 = 0.f, acc1 = 0.f;
    int e = beg;
    for (; e + 1 < end; e += 2) {
        int s0 = ssrc[e], s1 = ssrc[e + 1];
        float4 a0 = sea[e];
        float4 a1 = sea[e + 1];
        float2 q0 = *(const float2*)(PQ + (size_t)s0 * 256 + HD + j);
        float2 q1 = *(const float2*)(PQ + (size_t)s1 * 256 + HD + j);
        float z0 = p.x + q0.x + a0.x * wc0.x + a0.y * wc1.x + a0.z * wc2.x;
        float z1 = p.y + q0.y + a0.x * wc0.y + a0.y * wc1.y + a0.z * wc2.y;
        acc0 += fmaxf(z0, 0.f);
        acc1 += fmaxf(z1, 0.f);
        float z2 = p.x + q1.x + a1.x * wc0.x + a1.y * wc1.x + a1.z * wc2.x;
        float z3 = p.y + q1.y + a1.x * wc0.y + a1.y * wc1.y + a1.z * wc2.y;
        acc0 += fmaxf(z2, 0.f);
        acc1 += fmaxf(z3, 0.f);
    }
    if (e < end) {
        int s0 = ssrc[e];
        float4 a0 = sea[e];
        float2 q0 = *(const float2*)(PQ + (size_t)s0 * 256 + HD + j);
        float z0 = p.x + q0.x + a0.x * wc0.x + a0.y * wc1.x + a0.z * wc2.x;
        float z1 = p.y + q0.y + a0.x * wc0.y + a0.y * wc1.y + a0.z * wc2.y;
        acc0 += fmaxf(z0, 0.f);
        acc1 += fmaxf(z1, 0.f);
    }
    float iv = inv[n];
    S[(size_t)n * HD + j] = acc0 * iv;
    S[(size_t)n * HD + j + 1] = acc1 * iv;
}

// ---------------- fused update + residual + layernorm ----------------
// u_pre = h@U1a + S@M2 + ub1 + alpha*c2 ; t=relu(u_pre); u = t@upd_w2 + ub2 ; h = LN(u+h)*g+b

__global__ __launch_bounds__(256) void k_update(const float* __restrict__ hbuf, const float* __restrict__ S,
                                                const float* __restrict__ u1, const float* __restrict__ M2l,
                                                const float* __restrict__ ub1, const float* __restrict__ c2l,
                                                const float* __restrict__ w2u, const float* __restrict__ ub2,
                                                const float* __restrict__ g, const float* __restrict__ bb,
                                                const float* __restrict__ alpha, float* __restrict__ hout) {
    __shared__ float atile[16][256];
    int tid = threadIdx.x;
    int row0 = blockIdx.x * 16;
    {
        const float4* h4 = (const float4*)hbuf;
        const float4* S4 = (const float4*)S;
        float4* d = (float4*)&atile[0][0];
        for (int i = tid; i < 1024; i += 256) {
            int r = i >> 6, c = i & 63;
            float4 v = (c < 32) ? h4[(size_t)(row0 + r) * 32 + c] : S4[(size_t)(row0 + r) * 32 + (c - 32)];
            d[(size_t)r * 64 + c] = v;
        }
    }
    __syncthreads();
    int wid = tid >> 6, lane = tid & 63;
    int j = lane * 2;
    int r0 = wid * 4;
    float2 acc[4] = {{0, 0}, {0, 0}, {0, 0}, {0, 0}};
    for (int k = 0; k < HD; ++k) {
        float2 w = *(const float2*)(u1 + (size_t)k * HD + j);
#pragma unroll
        for (int r = 0; r < 4; ++r) {
            float xv = atile[r0 + r][k];
            acc[r].x += xv * w.x;
            acc[r].y += xv * w.y;
        }
    }
    for (int k = 0; k < HD; ++k) {
        float2 w = *(const float2*)(M2l + (size_t)k * HD + j);
#pragma unroll
        for (int r = 0; r < 4; ++r) {
            float xv = atile[r0 + r][HD + k];
            acc[r].x += xv * w.x;
            acc[r].y += xv * w.y;
        }
    }
    float2 ub = *(const float2*)(ub1 + j);
    float2 cc = *(const float2*)(c2l + j);
    float hres[4][2];
#pragma unroll
    for (int r = 0; r < 4; ++r) {
        float al = alpha[row0 + r0 + r];
        float t0 = fmaxf(acc[r].x + ub.x + al * cc.x, 0.f);
        float t1 = fmaxf(acc[r].y + ub.y + al * cc.y, 0.f);
        hres[r][0] = atile[r0 + r][j];
        hres[r][1] = atile[r0 + r][j + 1];
        atile[r0 + r][j] = t0;      // overwrite h-half with t (rows are wave-private)
        atile[r0 + r][j + 1] = t1;
    }
    __syncthreads();
    float2 acc2[4] = {{0, 0}, {0, 0}, {0, 0}, {0, 0}};
    for (int k = 0; k < HD; ++k) {
        float2 w = *(const float2*)(w2u + (size_t)k * HD + j);
#pragma unroll
        for (int r = 0; r < 4; ++r) {
            float xv = atile[r0 + r][k];
            acc2[r].x += xv * w.x;
            acc2[r].y += xv * w.y;
        }
    }
    float2 u2b = *(const float2*)(ub2 + j);
    float2 gg = *(const float2*)(g + j);
    float2 bbv = *(const float2*)(bb + j);
#pragma unroll
    for (int r = 0; r < 4; ++r) {
        float v0 = acc2[r].x + u2b.x + hres[r][0];
        float v1 = acc2[r].y + u2b.y + hres[r][1];
        float s = v0 + v1, sq = v0 * v0 + v1 * v1;
        for (int m = 1; m < 64; m <<= 1) {
            s += __shfl_xor(s, m);
            sq += __shfl_xor(sq, m);
        }
        float mu = s * (1.f / HD);
        float var = sq * (1.f / HD) - mu * mu;
        float rstd = rsqrtf(var + LN_EPS);
        float o0 = (v0 - mu) * rstd * gg.x + bbv.x;
        float o1 = (v1 - mu) * rstd * gg.y + bbv.y;
        hout[(size_t)(row0 + r0 + r) * HD + j] = o0;
        hout[(size_t)(row0 + r0 + r) * HD + j + 1] = o1;
    }
}

// ---------------- decoder ----------------

__global__ __launch_bounds__(256) void k_decoder(const float* __restrict__ h, const float* __restrict__ w1,
                                                 const float* __restrict__ b1, const float* __restrict__ w2,
                                                 const float* __restrict__ b2, float* __restrict__ out) {
    __shared__ float tb[4][128];
    int tid = threadIdx.x, wid = tid >> 6, lane = tid & 63;
    int n = blockIdx.x * 4 + wid;
    int j = lane * 2;
    float2 hv = *(const float2*)(h + (size_t)n * HD + j);
    tb[wid][j] = hv.x;
    tb[wid][j + 1] = hv.y;
    __syncthreads();
    float a0 = b1[j], a1 = b1[j + 1];
    for (int k = 0; k < HD; ++k) {
        float xx = tb[wid][k];
        float2 w = *(const float2*)(w1 + (size_t)k * HD + j);
        a0 += xx * w.x;
        a1 += xx * w.y;
    }
    a0 = fmaxf(a0, 0.f);
    a1 = fmaxf(a1, 0.f);
    float s = a0 * w2[j] + a1 * w2[j + 1];
    for (int m = 1; m < 64; m <<= 1) s += __shfl_xor(s, m);
    if (lane == 0) out[n] = s + b2[0];
}

// ---------------- launch ----------------

extern "C" void kernel_launch(void* const* d_in, const int* in_sizes, int n_in,
                              void* d_out, int out_size, void* d_ws, size_t ws_size,
                              hipStream_t stream) {
    const float* x = (const float*)d_in[0];
    const int* eidx = (const int*)d_in[1];
    const float* eattr = (const float*)d_in[2];
    const float* enc_w1 = (const float*)d_in[3];
    const float* enc_b1 = (const float*)d_in[4];
    const float* enc_w2 = (const float*)d_in[5];
    const float* enc_b2 = (const float*)d_in[6];
    const float* msg_w1 = (const float*)d_in[7];
    const float* msg_b1 = (const float*)d_in[8];
    const float* msg_w2 = (const float*)d_in[9];
    const float* msg_b2 = (const float*)d_in[10];
    const float* upd_w1 = (const float*)d_in[11];
    const float* upd_b1 = (const float*)d_in[12];
    const float* upd_w2 = (const float*)d_in[13];
    const float* upd_b2 = (const float*)d_in[14];
    const float* ln_g = (const float*)d_in[15];
    const float* ln_b = (const float*)d_in[16];
    const float* dec_w1 = (const float*)d_in[17];
    const float* dec_b1 = (const float*)d_in[18];
    const float* dec_w2 = (const float*)d_in[19];
    const float* dec_b2 = (const float*)d_in[20];
    const int* srcp = eidx;
    const int* tgtp = eidx + NE;

    float* ws = (float*)d_ws;
    size_t off = 0;
    float* h = ws + off;    off += (size_t)NN * HD;
    float* PQ = ws + off;   off += (size_t)NN * 2 * HD;
    float* S = ws + off;    off += (size_t)NN * HD;
    float* M2 = ws + off;   off += (size_t)NL * HD * HD;
    float* c2 = ws + off;   off += (size_t)NL * HD;
    float* inv = ws + off;  off += NN;
    float* alpha = ws + off; off += NN;
    float4* sea = (float4*)(ws + off); off += (size_t)NE * 4;
    int* counts = (int*)(ws + off);  off += NN;
    int* offsets = (int*)(ws + off); off += NN + 1;
    int* cursor = (int*)(ws + off);  off += NN;
    int* ssrc = (int*)(ws + off);    off += NE;

    k_zero_counts<<<(NN + 255) / 256, 256, 0, stream>>>(counts);
    k_count<<<(NE + 255) / 256, 256, 0, stream>>>(tgtp, counts);
    k_scan<<<1, 1024, 0, stream>>>(counts, offsets, cursor, inv, alpha);
    k_scatter<<<(NE + 255) / 256, 256, 0, stream>>>(srcp, tgtp, eattr, cursor, ssrc, sea);
    k_prep_m2<<<NL * HD * HD / 256, 256, 0, stream>>>(msg_w2, upd_w1, M2);
    k_prep_c2<<<(NL * HD + 255) / 256, 256, 0, stream>>>(msg_b2, upd_w1, c2);
    k_encoder<<<NN / 4, 256, 0, stream>>>(x, enc_w1, enc_b1, enc_w2, enc_b2, h);
    for (int l = 0; l < NL; ++l) {
        const float* w1l = msg_w1 + (size_t)l * (2 * HD + EDIM) * HD;
        k_pq<<<NN / 16, 256, 0, stream>>>(h, w1l, msg_b1 + l * HD, PQ);
        k_edge<<<NN / 4, 256, 0, stream>>>(PQ, offsets, ssrc, sea, w1l, inv, S);
        k_update<<<NN / 16, 256, 0, stream>>>(h, S, upd_w1 + (size_t)l * 2 * HD * HD,
                                              M2 + (size_t)l * HD * HD, upd_b1 + l * HD, c2 + l * HD,
                                              upd_w2 + (size_t)l * HD * HD, upd_b2 + l * HD,
                                              ln_g + l * HD, ln_b + l * HD, alpha, h);
    }
    k_decoder<<<NN / 4, 256, 0, stream>>>(h, dec_w1, dec_b1, dec_w2, dec_b2, (float*)d_out);
}

// Round 2
// 556.471 us; speedup vs baseline: 1.1617x; 1.1617x over previous
//
#include <hip/hip_runtime.h>

#define NN 10000
#define NE 400000
#define HD 128
#define NIN 6
#define EDIM 3
#define NL 4
#define LN_EPS 1e-5f

// ---------------- preprocessing ----------------

__global__ __launch_bounds__(256) void k_zero(int* counts) {
    int i = blockIdx.x * 256 + threadIdx.x;
    if (i < NN) counts[i] = 0;
}

__global__ __launch_bounds__(256) void k_count(const int* __restrict__ tgt, int* __restrict__ counts) {
    int e = blockIdx.x * 256 + threadIdx.x;
    if (e < NE) atomicAdd(&counts[tgt[e]], 1);
}

// shuffle-based scan: 10 chunks x 3 barriers instead of 200
__global__ __launch_bounds__(1024) void k_scan(const int* __restrict__ counts, int* __restrict__ offsets,
                                               int* __restrict__ cursor, float* __restrict__ inv,
                                               float* __restrict__ alpha) {
    __shared__ int wsum[16];
    int tid = threadIdx.x, wid = tid >> 6, lane = tid & 63;
    int base = 0;
    for (int start = 0; start < NN; start += 1024) {
        int i = start + tid;
        int c = (i < NN) ? counts[i] : 0;
        int s = c;
        for (int d = 1; d < 64; d <<= 1) {
            int v = __shfl_up(s, d);
            if (lane >= d) s += v;
        }
        if (lane == 63) wsum[wid] = s;
        __syncthreads();
        if (tid < 16) {
            int sc = wsum[tid];
            for (int d = 1; d < 16; d <<= 1) {
                int u = __shfl_up(sc, d);
                if (tid >= d) sc += u;
            }
            wsum[tid] = sc;
        }
        __syncthreads();
        int woff = (wid > 0) ? wsum[wid - 1] : 0;
        int total = wsum[15];
        if (i < NN) {
            int excl = base + woff + s - c;
            offsets[i] = excl;
            cursor[i] = excl;
            inv[i] = 1.0f / fmaxf((float)c, 1.0f);
            alpha[i] = (c > 0) ? 1.0f : 0.0f;
        }
        base += total;
        __syncthreads();
    }
    if (tid == 0) offsets[NN] = base;
}

__global__ __launch_bounds__(256) void k_scatter(const int* __restrict__ src, const int* __restrict__ tgt,
                                                 const float* __restrict__ ea, int* __restrict__ cursor,
                                                 int* __restrict__ ssrc, float4* __restrict__ sea) {
    int e = blockIdx.x * 256 + threadIdx.x;
    if (e >= NE) return;
    int t = tgt[e];
    int pos = atomicAdd(&cursor[t], 1);
    ssrc[pos] = src[e];
    sea[pos] = make_float4(ea[e * 3], ea[e * 3 + 1], ea[e * 3 + 2], 0.f);
}

// M2 = msg_w2 @ U1b (rows 0..127) and c2 = msg_b2 @ U1b (row 128), merged
__global__ __launch_bounds__(256) void k_prep(const float* __restrict__ msg_w2, const float* __restrict__ msg_b2,
                                              const float* __restrict__ upd_w1, float* __restrict__ M2,
                                              float* __restrict__ c2) {
    int idx = blockIdx.x * 256 + threadIdx.x;  // 4*129*128 = 66048 exactly
    int l = idx / 16512;
    int rem = idx % 16512;
    int i = rem >> 7;
    int jj = rem & 127;
    const float* U1b = upd_w1 + (size_t)l * 2 * HD * HD + (size_t)HD * HD;
    float acc = 0.f;
    if (i < HD) {
        const float* W2 = msg_w2 + (size_t)l * HD * HD + (size_t)i * HD;
        for (int t = 0; t < HD; ++t) acc += W2[t] * U1b[t * HD + jj];
        M2[(size_t)l * HD * HD + (size_t)i * HD + jj] = acc;
    } else {
        const float* b2 = msg_b2 + l * HD;
        for (int t = 0; t < HD; ++t) acc += b2[t] * U1b[t * HD + jj];
        c2[l * HD + jj] = acc;
    }
}

// ---------------- encoder + PQ(0) fused: 16 nodes/block, 4 rows/wave, zero barriers ----------------

__global__ __launch_bounds__(256) void k_enc(const float* __restrict__ x, const float* __restrict__ ew1,
                                             const float* __restrict__ eb1, const float* __restrict__ ew2,
                                             const float* __restrict__ eb2, const float* __restrict__ mw1,
                                             const float* __restrict__ mb1, float* __restrict__ h,
                                             float* __restrict__ PQ) {
    __shared__ float tS[16][HD];
    int tid = threadIdx.x, wid = tid >> 6, lane = tid & 63;
    int r0 = wid * 4;
    int nb = blockIdx.x * 16;
    int j = lane * 2;
    // GEMM1 (6->128) + relu, per row
#pragma unroll
    for (int r = 0; r < 4; ++r) {
        int n = nb + r0 + r;
        float t0 = eb1[j], t1 = eb1[j + 1];
#pragma unroll
        for (int k = 0; k < NIN; ++k) {
            float xk = x[(size_t)n * NIN + k];
            float2 w = *(const float2*)(ew1 + k * HD + j);
            t0 += xk * w.x;
            t1 += xk * w.y;
        }
        tS[r0 + r][j] = fmaxf(t0, 0.f);
        tS[r0 + r][j + 1] = fmaxf(t1, 0.f);
    }
    // GEMM2 (128->128): h
    float2 eb = *(const float2*)(eb2 + j);
    float2 acc[4];
#pragma unroll
    for (int r = 0; r < 4; ++r) acc[r] = eb;
    for (int k = 0; k < HD; ++k) {
        float2 w = *(const float2*)(ew2 + k * HD + j);
#pragma unroll
        for (int r = 0; r < 4; ++r) {
            float tk = tS[r0 + r][k];
            acc[r].x += tk * w.x;
            acc[r].y += tk * w.y;
        }
    }
#pragma unroll
    for (int r = 0; r < 4; ++r) {
        *(float2*)(h + (size_t)(nb + r0 + r) * HD + j) = acc[r];
        tS[r0 + r][j] = acc[r].x;       // overwrite t with h (own-wave rows)
        tS[r0 + r][j + 1] = acc[r].y;
    }
    // PQ(0) = h @ [W1a | W1b] (+ b1 on P half)
    int j2 = lane * 4;
    const float* Bb = (j2 < HD) ? (mw1 + j2) : (mw1 + (size_t)HD * HD + (j2 - HD));
    float4 bias = (j2 < HD) ? *(const float4*)(mb1 + j2) : make_float4(0, 0, 0, 0);
    float4 a4[4];
#pragma unroll
    for (int r = 0; r < 4; ++r) a4[r] = bias;
    for (int k = 0; k < HD; ++k) {
        float4 w = *(const float4*)(Bb + (size_t)k * HD);
#pragma unroll
        for (int r = 0; r < 4; ++r) {
            float hk = tS[r0 + r][k];
            a4[r].x += hk * w.x; a4[r].y += hk * w.y; a4[r].z += hk * w.z; a4[r].w += hk * w.w;
        }
    }
#pragma unroll
    for (int r = 0; r < 4; ++r) *(float4*)(PQ + (size_t)(nb + r0 + r) * 256 + j2) = a4[r];
}

// ---------------- edge phase: wave per node, 4-edge unroll ----------------

__global__ __launch_bounds__(256) void k_edge(const float* __restrict__ PQ, const int* __restrict__ offsets,
                                              const int* __restrict__ ssrc, const float4* __restrict__ sea,
                                              const float* __restrict__ w1, const float* __restrict__ inv,
                                              float* __restrict__ S) {
    int n = blockIdx.x * 4 + (threadIdx.x >> 6);
    int lane = threadIdx.x & 63;
    int j = lane * 2;
    float2 p = *(const float2*)(PQ + (size_t)n * 256 + j);
    const float* wc = w1 + (size_t)(2 * HD) * HD;
    float2 wc0 = *(const float2*)(wc + j);
    float2 wc1 = *(const float2*)(wc + HD + j);
    float2 wc2 = *(const float2*)(wc + 2 * HD + j);
    int beg = offsets[n], end = offsets[n + 1];
    float acc0 = 0.f, acc1 = 0.f;
    int e = beg;
    for (; e + 3 < end; e += 4) {
        int s0 = ssrc[e], s1 = ssrc[e + 1], s2 = ssrc[e + 2], s3 = ssrc[e + 3];
        float4 A0 = sea[e], A1 = sea[e + 1], A2 = sea[e + 2], A3 = sea[e + 3];
        float2 q0 = *(const float2*)(PQ + (size_t)s0 * 256 + HD + j);
        float2 q1 = *(const float2*)(PQ + (size_t)s1 * 256 + HD + j);
        float2 q2 = *(const float2*)(PQ + (size_t)s2 * 256 + HD + j);
        float2 q3 = *(const float2*)(PQ + (size_t)s3 * 256 + HD + j);
        acc0 += fmaxf(p.x + q0.x + A0.x * wc0.x + A0.y * wc1.x + A0.z * wc2.x, 0.f);
        acc1 += fmaxf(p.y + q0.y + A0.x * wc0.y + A0.y * wc1.y + A0.z * wc2.y, 0.f);
        acc0 += fmaxf(p.x + q1.x + A1.x * wc0.x + A1.y * wc1.x + A1.z * wc2.x, 0.f);
        acc1 += fmaxf(p.y + q1.y + A1.x * wc0.y + A1.y * wc1.y + A1.z * wc2.y, 0.f);
        acc0 += fmaxf(p.x + q2.x + A2.x * wc0.x + A2.y * wc1.x + A2.z * wc2.x, 0.f);
        acc1 += fmaxf(p.y + q2.y + A2.x * wc0.y + A2.y * wc1.y + A2.z * wc2.y, 0.f);
        acc0 += fmaxf(p.x + q3.x + A3.x * wc0.x + A3.y * wc1.x + A3.z * wc2.x, 0.f);
        acc1 += fmaxf(p.y + q3.y + A3.x * wc0.y + A3.y * wc1.y + A3.z * wc2.y, 0.f);
    }
    for (; e < end; ++e) {
        int s0 = ssrc[e];
        float4 A0 = sea[e];
        float2 q0 = *(const float2*)(PQ + (size_t)s0 * 256 + HD + j);
        acc0 += fmaxf(p.x + q0.x + A0.x * wc0.x + A0.y * wc1.x + A0.z * wc2.x, 0.f);
        acc1 += fmaxf(p.y + q0.y + A0.x * wc0.y + A0.y * wc1.y + A0.z * wc2.y, 0.f);
    }
    float iv = inv[n];
    S[(size_t)n * HD + j] = acc0 * iv;
    S[(size_t)n * HD + j + 1] = acc1 * iv;
}

// ---------------- fused update + LN + (next PQ | decoder): 16 nodes/block, zero barriers --------

template <bool LAST>
__global__ __launch_bounds__(256) void k_upd(
    float* __restrict__ h, const float* __restrict__ S,
    const float* __restrict__ u1, const float* __restrict__ M2l,
    const float* __restrict__ ub1, const float* __restrict__ c2l,
    const float* __restrict__ w2u, const float* __restrict__ ub2,
    const float* __restrict__ g, const float* __restrict__ bb,
    const float* __restrict__ alpha,
    const float* __restrict__ nxt_w1, const float* __restrict__ nxt_b1, float* __restrict__ PQ,
    const float* __restrict__ dw1, const float* __restrict__ db1,
    const float* __restrict__ dw2, const float* __restrict__ db2, float* __restrict__ out) {
    __shared__ float smem[16][2][HD];  // [row][0]=h, [row][1]=S then t
    int tid = threadIdx.x, wid = tid >> 6, lane = tid & 63;
    int r0 = wid * 4;
    int nb = blockIdx.x * 16;
    int j = lane * 2;
    // wave-private load of 4 rows of h and S
    {
        const float4* h4 = (const float4*)(h + (size_t)(nb + r0) * HD);
        const float4* S4 = (const float4*)(S + (size_t)(nb + r0) * HD);
        for (int i = lane; i < 128; i += 64) {
            int r = i >> 5, c = i & 31;
            *((float4*)&smem[r0 + r][0][0] + c) = h4[i];
            *((float4*)&smem[r0 + r][1][0] + c) = S4[i];
        }
    }
    // GEMM1: u_pre = h@U1a + S@M2 + ub1 + alpha*c2
    float2 ub = *(const float2*)(ub1 + j);
    float2 cc = *(const float2*)(c2l + j);
    float2 acc1[4];
#pragma unroll
    for (int r = 0; r < 4; ++r) {
        float al = alpha[nb + r0 + r];
        acc1[r].x = ub.x + al * cc.x;
        acc1[r].y = ub.y + al * cc.y;
    }
    for (int k = 0; k < HD; ++k) {
        float2 wu = *(const float2*)(u1 + k * HD + j);
        float2 wm = *(const float2*)(M2l + k * HD + j);
#pragma unroll
        for (int r = 0; r < 4; ++r) {
            float hk = smem[r0 + r][0][k];
            float sk = smem[r0 + r][1][k];
            acc1[r].x += hk * wu.x + sk * wm.x;
            acc1[r].y += hk * wu.y + sk * wm.y;
        }
    }
#pragma unroll
    for (int r = 0; r < 4; ++r) {
        smem[r0 + r][1][j] = fmaxf(acc1[r].x, 0.f);
        smem[r0 + r][1][j + 1] = fmaxf(acc1[r].y, 0.f);
    }
    // GEMM2: u = t @ w2u + ub2
    float2 u2b = *(const float2*)(ub2 + j);
    float2 acc2[4];
#pragma unroll
    for (int r = 0; r < 4; ++r) acc2[r] = u2b;
    for (int k = 0; k < HD; ++k) {
        float2 w = *(const float2*)(w2u + k * HD + j);
#pragma unroll
        for (int r = 0; r < 4; ++r) {
            float tk = smem[r0 + r][1][k];
            acc2[r].x += tk * w.x;
            acc2[r].y += tk * w.y;
        }
    }
    // residual + layernorm -> h'
    float2 gg = *(const float2*)(g + j), bv = *(const float2*)(bb + j);
#pragma unroll
    for (int r = 0; r < 4; ++r) {
        float v0 = acc2[r].x + smem[r0 + r][0][j];
        float v1 = acc2[r].y + smem[r0 + r][0][j + 1];
        float s = v0 + v1, sq = v0 * v0 + v1 * v1;
        for (int m = 1; m < 64; m <<= 1) {
            s += __shfl_xor(s, m);
            sq += __shfl_xor(sq, m);
        }
        float mu = s * (1.f / HD);
        float var = sq * (1.f / HD) - mu * mu;
        float rstd = rsqrtf(var + LN_EPS);
        float o0 = (v0 - mu) * rstd * gg.x + bv.x;
        float o1 = (v1 - mu) * rstd * gg.y + bv.y;
        smem[r0 + r][0][j] = o0;
        smem[r0 + r][0][j + 1] = o1;
        *(float2*)(h + (size_t)(nb + r0 + r) * HD + j) = make_float2(o0, o1);
    }
    if (!LAST) {
        // PQ(next) = h' @ [W1a | W1b] (+ b1 on P half)
        int j2 = lane * 4;
        const float* Bb = (j2 < HD) ? (nxt_w1 + j2) : (nxt_w1 + (size_t)HD * HD + (j2 - HD));
        float4 bias = (j2 < HD) ? *(const float4*)(nxt_b1 + j2) : make_float4(0, 0, 0, 0);
        float4 a4[4];
#pragma unroll
        for (int r = 0; r < 4; ++r) a4[r] = bias;
        for (int k = 0; k < HD; ++k) {
            float4 w = *(const float4*)(Bb + (size_t)k * HD);
#pragma unroll
            for (int r = 0; r < 4; ++r) {
                float hk = smem[r0 + r][0][k];
                a4[r].x += hk * w.x; a4[r].y += hk * w.y; a4[r].z += hk * w.z; a4[r].w += hk * w.w;
            }
        }
#pragma unroll
        for (int r = 0; r < 4; ++r) *(float4*)(PQ + (size_t)(nb + r0 + r) * 256 + j2) = a4[r];
    } else {
        // decoder: relu(h'@dw1+db1)@dw2+db2
        float2 d1b = *(const float2*)(db1 + j);
        float2 acc[4];
#pragma unroll
        for (int r = 0; r < 4; ++r) acc[r] = d1b;
        for (int k = 0; k < HD; ++k) {
            float2 w = *(const float2*)(dw1 + k * HD + j);
#pragma unroll
            for (int r = 0; r < 4; ++r) {
                float hk = smem[r0 + r][0][k];
                acc[r].x += hk * w.x;
                acc[r].y += hk * w.y;
            }
        }
        float2 w2v = *(const float2*)(dw2 + j);
#pragma unroll
        for (int r = 0; r < 4; ++r) {
            float val = fmaxf(acc[r].x, 0.f) * w2v.x + fmaxf(acc[r].y, 0.f) * w2v.y;
            for (int m = 1; m < 64; m <<= 1) val += __shfl_xor(val, m);
            if (lane == 0) out[nb + r0 + r] = val + db2[0];
        }
    }
}

// ---------------- launch ----------------

extern "C" void kernel_launch(void* const* d_in, const int* in_sizes, int n_in,
                              void* d_out, int out_size, void* d_ws, size_t ws_size,
                              hipStream_t stream) {
    const float* x = (const float*)d_in[0];
    const int* eidx = (const int*)d_in[1];
    const float* eattr = (const float*)d_in[2];
    const float* enc_w1 = (const float*)d_in[3];
    const float* enc_b1 = (const float*)d_in[4];
    const float* enc_w2 = (const float*)d_in[5];
    const float* enc_b2 = (const float*)d_in[6];
    const float* msg_w1 = (const float*)d_in[7];
    const float* msg_b1 = (const float*)d_in[8];
    const float* msg_w2 = (const float*)d_in[9];
    const float* msg_b2 = (const float*)d_in[10];
    const float* upd_w1 = (const float*)d_in[11];
    const float* upd_b1 = (const float*)d_in[12];
    const float* upd_w2 = (const float*)d_in[13];
    const float* upd_b2 = (const float*)d_in[14];
    const float* ln_g = (const float*)d_in[15];
    const float* ln_b = (const float*)d_in[16];
    const float* dec_w1 = (const float*)d_in[17];
    const float* dec_b1 = (const float*)d_in[18];
    const float* dec_w2 = (const float*)d_in[19];
    const float* dec_b2 = (const float*)d_in[20];
    const int* srcp = eidx;
    const int* tgtp = eidx + NE;

    float* ws = (float*)d_ws;
    size_t off = 0;
    float* h = ws + off;    off += (size_t)NN * HD;
    float* PQ = ws + off;   off += (size_t)NN * 2 * HD;
    float* S = ws + off;    off += (size_t)NN * HD;
    float* M2 = ws + off;   off += (size_t)NL * HD * HD;
    float* c2 = ws + off;   off += (size_t)NL * HD;
    float* inv = ws + off;  off += NN;
    float* alpha = ws + off; off += NN + 2;  // keep sea 16B-aligned
    float4* sea = (float4*)(ws + off); off += (size_t)NE * 4;
    int* counts = (int*)(ws + off);  off += NN;
    int* offsets = (int*)(ws + off); off += NN + 1;
    int* cursor = (int*)(ws + off);  off += NN;
    int* ssrc = (int*)(ws + off);    off += NE;

    k_zero<<<(NN + 255) / 256, 256, 0, stream>>>(counts);
    k_count<<<(NE + 255) / 256, 256, 0, stream>>>(tgtp, counts);
    k_scan<<<1, 1024, 0, stream>>>(counts, offsets, cursor, inv, alpha);
    k_scatter<<<(NE + 255) / 256, 256, 0, stream>>>(srcp, tgtp, eattr, cursor, ssrc, sea);
    k_prep<<<NL * 129 * HD / 256, 256, 0, stream>>>(msg_w2, msg_b2, upd_w1, M2, c2);
    k_enc<<<NN / 16, 256, 0, stream>>>(x, enc_w1, enc_b1, enc_w2, enc_b2, msg_w1, msg_b1, h, PQ);
    for (int l = 0; l < NL; ++l) {
        const float* w1l = msg_w1 + (size_t)l * (2 * HD + EDIM) * HD;
        k_edge<<<NN / 4, 256, 0, stream>>>(PQ, offsets, ssrc, sea, w1l, inv, S);
        if (l < NL - 1) {
            k_upd<false><<<NN / 16, 256, 0, stream>>>(
                h, S, upd_w1 + (size_t)l * 2 * HD * HD, M2 + (size_t)l * HD * HD,
                upd_b1 + l * HD, c2 + l * HD, upd_w2 + (size_t)l * HD * HD, upd_b2 + l * HD,
                ln_g + l * HD, ln_b + l * HD, alpha,
                msg_w1 + (size_t)(l + 1) * (2 * HD + EDIM) * HD, msg_b1 + (l + 1) * HD, PQ,
                nullptr, nullptr, nullptr, nullptr, nullptr);
        } else {
            k_upd<true><<<NN / 16, 256, 0, stream>>>(
                h, S, upd_w1 + (size_t)l * 2 * HD * HD, M2 + (size_t)l * HD * HD,
                upd_b1 + l * HD, c2 + l * HD, upd_w2 + (size_t)l * HD * HD, upd_b2 + l * HD,
                ln_g + l * HD, ln_b + l * HD, alpha,
                nullptr, nullptr, nullptr,
                dec_w1, dec_b1, dec_w2, dec_b2, (float*)d_out);
        }
    }
}

// Round 3
// 356.384 us; speedup vs baseline: 1.8140x; 1.5614x over previous
//
#include <hip/hip_runtime.h>

#define NN 10000
#define NE 400000
#define HD 128
#define NIN 6
#define EDIM 3
#define NL 4
#define LN_EPS 1e-5f

typedef unsigned short u16;
using short8 = __attribute__((ext_vector_type(8))) short;
using f32x4 = __attribute__((ext_vector_type(4))) float;

__device__ __forceinline__ u16 f2bf(float x) {
    unsigned u = __float_as_uint(x);
    return (u16)((u + 0x7fff + ((u >> 16) & 1)) >> 16);
}
__device__ __forceinline__ float bf2f(u16 h) { return __uint_as_float(((unsigned)h) << 16); }
__device__ __forceinline__ void split2(float x, u16& hi, u16& lo) {
    hi = f2bf(x);
    lo = f2bf(x - bf2f(hi));
}
#define MFMA(a, b, c) __builtin_amdgcn_mfma_f32_16x16x32_bf16((a), (b), (c), 0, 0, 0)

// ---------------- preprocessing (unchanged from R2) ----------------

__global__ __launch_bounds__(256) void k_zero(int* counts) {
    int i = blockIdx.x * 256 + threadIdx.x;
    if (i < NN) counts[i] = 0;
}

__global__ __launch_bounds__(256) void k_count(const int* __restrict__ tgt, int* __restrict__ counts) {
    int e = blockIdx.x * 256 + threadIdx.x;
    if (e < NE) atomicAdd(&counts[tgt[e]], 1);
}

__global__ __launch_bounds__(1024) void k_scan(const int* __restrict__ counts, int* __restrict__ offsets,
                                               int* __restrict__ cursor, float* __restrict__ inv,
                                               float* __restrict__ alpha) {
    __shared__ int wsum[16];
    int tid = threadIdx.x, wid = tid >> 6, lane = tid & 63;
    int base = 0;
    for (int start = 0; start < NN; start += 1024) {
        int i = start + tid;
        int c = (i < NN) ? counts[i] : 0;
        int s = c;
        for (int d = 1; d < 64; d <<= 1) {
            int v = __shfl_up(s, d);
            if (lane >= d) s += v;
        }
        if (lane == 63) wsum[wid] = s;
        __syncthreads();
        if (tid < 16) {
            int sc = wsum[tid];
            for (int d = 1; d < 16; d <<= 1) {
                int u = __shfl_up(sc, d);
                if (tid >= d) sc += u;
            }
            wsum[tid] = sc;
        }
        __syncthreads();
        int woff = (wid > 0) ? wsum[wid - 1] : 0;
        int total = wsum[15];
        if (i < NN) {
            int excl = base + woff + s - c;
            offsets[i] = excl;
            cursor[i] = excl;
            inv[i] = 1.0f / fmaxf((float)c, 1.0f);
            alpha[i] = (c > 0) ? 1.0f : 0.0f;
        }
        base += total;
        __syncthreads();
    }
    if (tid == 0) offsets[NN] = base;
}

__global__ __launch_bounds__(256) void k_scatter(const int* __restrict__ src, const int* __restrict__ tgt,
                                                 const float* __restrict__ ea, int* __restrict__ cursor,
                                                 int* __restrict__ ssrc, float4* __restrict__ sea) {
    int e = blockIdx.x * 256 + threadIdx.x;
    if (e >= NE) return;
    int t = tgt[e];
    int pos = atomicAdd(&cursor[t], 1);
    ssrc[pos] = src[e];
    sea[pos] = make_float4(ea[e * 3], ea[e * 3 + 1], ea[e * 3 + 2], 0.f);
}

__global__ __launch_bounds__(256) void k_prep(const float* __restrict__ msg_w2, const float* __restrict__ msg_b2,
                                              const float* __restrict__ upd_w1, float* __restrict__ M2,
                                              float* __restrict__ c2) {
    int idx = blockIdx.x * 256 + threadIdx.x;  // 4*129*128 = 66048
    int l = idx / 16512;
    int rem = idx % 16512;
    int i = rem >> 7;
    int jj = rem & 127;
    const float* U1b = upd_w1 + (size_t)l * 2 * HD * HD + (size_t)HD * HD;
    float acc = 0.f;
    if (i < HD) {
        const float* W2 = msg_w2 + (size_t)l * HD * HD + (size_t)i * HD;
        for (int t = 0; t < HD; ++t) acc += W2[t] * U1b[t * HD + jj];
        M2[(size_t)l * HD * HD + (size_t)i * HD + jj] = acc;
    } else {
        const float* b2 = msg_b2 + l * HD;
        for (int t = 0; t < HD; ++t) acc += b2[t] * U1b[t * HD + jj];
        c2[l * HD + jj] = acc;
    }
}

// ---------------- weight fragmentization: B-frag layout [ct][ks][lane][8] bf16 -----------
// B[k][n]: lane holds n = ct*16 + (lane&15), k = ks*32 + (lane>>4)*8 + j
// regions: G1 (4 layers, [U1a;M2] 256x128), G2 (w2u 128x128), PQ (mw1 as 128x256, 4 slots),
//          DEC (dec_w1 128x128), ENC (enc_w2 128x128). total groups 45056 = 176*256.

__global__ __launch_bounds__(256) void k_frag(const float* __restrict__ upd_w1, const float* __restrict__ M2,
                                              const float* __restrict__ upd_w2, const float* __restrict__ msg_w1,
                                              const float* __restrict__ dec_w1, const float* __restrict__ enc_w2,
                                              u16* __restrict__ fG1, u16* __restrict__ fG2, u16* __restrict__ fPQ,
                                              u16* __restrict__ fDec, u16* __restrict__ fEnc) {
    int g = blockIdx.x * 256 + threadIdx.x;
    if (g < 16384) {
        int l = g >> 12, r = g & 4095;
        int ct = r >> 9, ks = (r >> 6) & 7, lane = r & 63;
        int n = ct * 16 + (lane & 15), kb = ks * 32 + ((lane >> 4) << 3);
        u16* dst = fG1 + (size_t)g * 8;
        const float* U = upd_w1 + (size_t)l * 256 * 128;
        const float* Ml = M2 + (size_t)l * 128 * 128;
#pragma unroll
        for (int j = 0; j < 8; ++j) {
            int k = kb + j;
            float v = (k < 128) ? U[(size_t)k * 128 + n] : Ml[(size_t)(k - 128) * 128 + n];
            dst[j] = f2bf(v);
        }
    } else if (g < 24576) {
        int gg = g - 16384;
        int l = gg >> 11, r = gg & 2047;
        int ct = r >> 8, ks = (r >> 6) & 3, lane = r & 63;
        int n = ct * 16 + (lane & 15), kb = ks * 32 + ((lane >> 4) << 3);
        u16* dst = fG2 + (size_t)gg * 8;
        const float* W = upd_w2 + (size_t)l * 128 * 128;
#pragma unroll
        for (int j = 0; j < 8; ++j) dst[j] = f2bf(W[(size_t)(kb + j) * 128 + n]);
    } else if (g < 40960) {
        int gg = g - 24576;
        int li = gg >> 12, r = gg & 4095;
        int ct = r >> 8, ks = (r >> 6) & 3, lane = r & 63;
        int n = ct * 16 + (lane & 15), kb = ks * 32 + ((lane >> 4) << 3);
        u16* dst = fPQ + (size_t)gg * 8;
        const float* W = msg_w1 + (size_t)li * (2 * HD + EDIM) * HD;
#pragma unroll
        for (int j = 0; j < 8; ++j) {
            int k = kb + j;
            float v = (n < 128) ? W[(size_t)k * 128 + n] : W[(size_t)(128 + k) * 128 + (n - 128)];
            dst[j] = f2bf(v);
        }
    } else if (g < 43008) {
        int r = g - 40960;
        int ct = r >> 8, ks = (r >> 6) & 3, lane = r & 63;
        int n = ct * 16 + (lane & 15), kb = ks * 32 + ((lane >> 4) << 3);
        u16* dst = fDec + (size_t)r * 8;
#pragma unroll
        for (int j = 0; j < 8; ++j) dst[j] = f2bf(dec_w1[(size_t)(kb + j) * 128 + n]);
    } else {
        int r = g - 43008;
        int ct = r >> 8, ks = (r >> 6) & 3, lane = r & 63;
        int n = ct * 16 + (lane & 15), kb = ks * 32 + ((lane >> 4) << 3);
        u16* dst = fEnc + (size_t)r * 8;
#pragma unroll
        for (int j = 0; j < 8; ++j) dst[j] = f2bf(enc_w2[(size_t)(kb + j) * 128 + n]);
    }
}

// ---- shared LDS helpers: t/h' stored as bf16 hi/lo [16][128] with chunk-XOR swizzle ----
// write el (row16, col): chunkS = (col>>3) ^ row16 ; addr = row16*128 + chunkS*8 + (col&7)
// A-frag read (row=c, kstep ks): addr = c*128 + ((ks*4+q)^c)*8, 16B ds_read

// ---------------- encoder: GEMM1 VALU -> MFMA GEMM2 -> MFMA PQ0 ----------------

__global__ __launch_bounds__(256) void k_enc(const float* __restrict__ x, const float* __restrict__ ew1,
                                             const float* __restrict__ eb1, const u16* __restrict__ fEnc,
                                             const float* __restrict__ eb2, const u16* __restrict__ fPQ0,
                                             const float* __restrict__ mb1, u16* __restrict__ h_hi,
                                             u16* __restrict__ h_lo, float* __restrict__ PQf,
                                             u16* __restrict__ Qb) {
    __shared__ u16 tHi[2048], tLo[2048];
    int tid = threadIdx.x, w = tid >> 6, lane = tid & 63, q = lane >> 4, c = lane & 15;
    int band = blockIdx.x * 16;
    // GEMM1: t = relu(x@ew1 + eb1), per-wave cols [w*32, w*32+32)
#pragma unroll
    for (int i = 0; i < 2; ++i) {
        int ctg = w * 2 + i, col = ctg * 16 + c;
        float wv[NIN];
#pragma unroll
        for (int k = 0; k < NIN; ++k) wv[k] = ew1[k * HD + col];
        float ebv = eb1[col];
#pragma unroll
        for (int reg = 0; reg < 4; ++reg) {
            int row = band + q * 4 + reg;
            float t = ebv;
#pragma unroll
            for (int k = 0; k < NIN; ++k) t += x[(size_t)row * NIN + k] * wv[k];
            t = fmaxf(t, 0.f);
            u16 hi, lo;
            split2(t, hi, lo);
            int r16 = q * 4 + reg;
            int a = r16 * 128 + (((col >> 3) ^ r16) << 3) + (col & 7);
            tHi[a] = hi;
            tLo[a] = lo;
        }
    }
    __syncthreads();
    // GEMM2: h = t @ ew2 + eb2
    short8 aH[4], aL[4];
#pragma unroll
    for (int ks = 0; ks < 4; ++ks) {
        int a = c * 128 + (((ks * 4 + q) ^ c) << 3);
        aH[ks] = *(const short8*)&tHi[a];
        aL[ks] = *(const short8*)&tLo[a];
    }
    f32x4 acc[2] = {{0, 0, 0, 0}, {0, 0, 0, 0}};
#pragma unroll
    for (int i = 0; i < 2; ++i) {
        int ctg = w * 2 + i;
        const u16* fb = fEnc + (size_t)ctg * 4 * 512 + lane * 8;
#pragma unroll
        for (int ks = 0; ks < 4; ++ks) {
            short8 b = *(const short8*)(fb + ks * 512);
            acc[i] = MFMA(aH[ks], b, acc[i]);
            acc[i] = MFMA(aL[ks], b, acc[i]);
        }
    }
    __syncthreads();  // all t reads done before overwrite
#pragma unroll
    for (int i = 0; i < 2; ++i) {
        int ctg = w * 2 + i, col = ctg * 16 + c;
        float ebv = eb2[col];
#pragma unroll
        for (int reg = 0; reg < 4; ++reg) {
            int r16 = q * 4 + reg, row = band + r16;
            float hval = acc[i][reg] + ebv;
            u16 hi, lo;
            split2(hval, hi, lo);
            h_hi[(size_t)row * HD + col] = hi;
            h_lo[(size_t)row * HD + col] = lo;
            int a = r16 * 128 + (((col >> 3) ^ r16) << 3) + (col & 7);
            tHi[a] = hi;
            tLo[a] = lo;
        }
    }
    __syncthreads();
    // PQ0 = h @ [W1a|W1b] (+ mb1 on P half)
#pragma unroll
    for (int ks = 0; ks < 4; ++ks) {
        int a = c * 128 + (((ks * 4 + q) ^ c) << 3);
        aH[ks] = *(const short8*)&tHi[a];
        aL[ks] = *(const short8*)&tLo[a];
    }
#pragma unroll
    for (int i = 0; i < 4; ++i) {
        int ctg = w * 4 + i;
        const u16* fb = fPQ0 + (size_t)ctg * 4 * 512 + lane * 8;
        f32x4 a3 = {0, 0, 0, 0};
#pragma unroll
        for (int ks = 0; ks < 4; ++ks) {
            short8 b = *(const short8*)(fb + ks * 512);
            a3 = MFMA(aH[ks], b, a3);
            a3 = MFMA(aL[ks], b, a3);
        }
        int col = ctg * 16 + c;
        if (ctg < 8) {
            float bias = mb1[col];
#pragma unroll
            for (int reg = 0; reg < 4; ++reg)
                PQf[(size_t)(band + q * 4 + reg) * HD + col] = a3[reg] + bias;
        } else {
            int colq = col - 128;
#pragma unroll
            for (int reg = 0; reg < 4; ++reg)
                Qb[(size_t)(band + q * 4 + reg) * HD + colq] = f2bf(a3[reg]);
        }
    }
}

// ---------------- edge phase: wave/node, bf16 Q gathers, 4-edge unroll ----------------

__global__ __launch_bounds__(256) void k_edge(const float* __restrict__ PQf, const u16* __restrict__ Qb,
                                              const int* __restrict__ offsets, const int* __restrict__ ssrc,
                                              const float4* __restrict__ sea, const float* __restrict__ wc,
                                              const float* __restrict__ inv, u16* __restrict__ S_hi,
                                              u16* __restrict__ S_lo) {
    int n = blockIdx.x * 4 + (threadIdx.x >> 6);
    int lane = threadIdx.x & 63;
    int j = lane * 2;
    float2 p = *(const float2*)(PQf + (size_t)n * HD + j);
    float2 wc0 = *(const float2*)(wc + j);
    float2 wc1 = *(const float2*)(wc + HD + j);
    float2 wc2 = *(const float2*)(wc + 2 * HD + j);
    int beg = offsets[n], end = offsets[n + 1];
    float acc0 = 0.f, acc1 = 0.f;
    int e = beg;
    for (; e + 3 < end; e += 4) {
        int s0 = ssrc[e], s1 = ssrc[e + 1], s2 = ssrc[e + 2], s3 = ssrc[e + 3];
        float4 A0 = sea[e], A1 = sea[e + 1], A2 = sea[e + 2], A3 = sea[e + 3];
        ushort2 q0 = *(const ushort2*)(Qb + (size_t)s0 * HD + j);
        ushort2 q1 = *(const ushort2*)(Qb + (size_t)s1 * HD + j);
        ushort2 q2 = *(const ushort2*)(Qb + (size_t)s2 * HD + j);
        ushort2 q3 = *(const ushort2*)(Qb + (size_t)s3 * HD + j);
        acc0 += fmaxf(p.x + bf2f(q0.x) + A0.x * wc0.x + A0.y * wc1.x + A0.z * wc2.x, 0.f);
        acc1 += fmaxf(p.y + bf2f(q0.y) + A0.x * wc0.y + A0.y * wc1.y + A0.z * wc2.y, 0.f);
        acc0 += fmaxf(p.x + bf2f(q1.x) + A1.x * wc0.x + A1.y * wc1.x + A1.z * wc2.x, 0.f);
        acc1 += fmaxf(p.y + bf2f(q1.y) + A1.x * wc0.y + A1.y * wc1.y + A1.z * wc2.y, 0.f);
        acc0 += fmaxf(p.x + bf2f(q2.x) + A2.x * wc0.x + A2.y * wc1.x + A2.z * wc2.x, 0.f);
        acc1 += fmaxf(p.y + bf2f(q2.y) + A2.x * wc0.y + A2.y * wc1.y + A2.z * wc2.y, 0.f);
        acc0 += fmaxf(p.x + bf2f(q3.x) + A3.x * wc0.x + A3.y * wc1.x + A3.z * wc2.x, 0.f);
        acc1 += fmaxf(p.y + bf2f(q3.y) + A3.x * wc0.y + A3.y * wc1.y + A3.z * wc2.y, 0.f);
    }
    for (; e < end; ++e) {
        int s0 = ssrc[e];
        float4 A0 = sea[e];
        ushort2 q0 = *(const ushort2*)(Qb + (size_t)s0 * HD + j);
        acc0 += fmaxf(p.x + bf2f(q0.x) + A0.x * wc0.x + A0.y * wc1.x + A0.z * wc2.x, 0.f);
        acc1 += fmaxf(p.y + bf2f(q0.y) + A0.x * wc0.y + A0.y * wc1.y + A0.z * wc2.y, 0.f);
    }
    float iv = inv[n];
    float v0 = acc0 * iv, v1 = acc1 * iv;
    u16 h0, l0, h1, l1;
    split2(v0, h0, l0);
    split2(v1, h1, l1);
    *(ushort2*)(S_hi + (size_t)n * HD + j) = make_ushort2(h0, h1);
    *(ushort2*)(S_lo + (size_t)n * HD + j) = make_ushort2(l0, l1);
}

// ---------------- fused update: MFMA G1 -> relu -> MFMA G2 -> +res -> LN -> MFMA (PQ | dec) ----

template <bool LAST>
__global__ __launch_bounds__(256) void k_upd(
    u16* __restrict__ h_hi, u16* __restrict__ h_lo,
    const u16* __restrict__ S_hi, const u16* __restrict__ S_lo,
    const u16* __restrict__ fG1, const u16* __restrict__ fG2, const u16* __restrict__ fPQ,
    const float* __restrict__ ub1, const float* __restrict__ c2l, const float* __restrict__ ub2,
    const float* __restrict__ g, const float* __restrict__ bb, const float* __restrict__ alpha,
    const float* __restrict__ nb1, float* __restrict__ PQf, u16* __restrict__ Qb,
    const u16* __restrict__ fDec, const float* __restrict__ db1, const float* __restrict__ dw2,
    const float* __restrict__ db2, float* __restrict__ out) {
    __shared__ u16 tHi[2048], tLo[2048];
    __shared__ float red[16][4][2];
    int tid = threadIdx.x, w = tid >> 6, lane = tid & 63, q = lane >> 4, c = lane & 15;
    int band = blockIdx.x * 16;
    // ---- G1: A-frags from global h/S (hi/lo bf16, MFMA-ready) ----
    short8 aH[8], aL[8];
    {
        size_t rb = (size_t)(band + c) * HD + q * 8;
#pragma unroll
        for (int ks = 0; ks < 4; ++ks) {
            aH[ks] = *(const short8*)(h_hi + rb + ks * 32);
            aL[ks] = *(const short8*)(h_lo + rb + ks * 32);
            aH[4 + ks] = *(const short8*)(S_hi + rb + ks * 32);
            aL[4 + ks] = *(const short8*)(S_lo + rb + ks * 32);
        }
    }
    f32x4 acc[2] = {{0, 0, 0, 0}, {0, 0, 0, 0}};
#pragma unroll
    for (int i = 0; i < 2; ++i) {
        int ctg = w * 2 + i;
        const u16* fb = fG1 + (size_t)ctg * 8 * 512 + lane * 8;
#pragma unroll
        for (int ks = 0; ks < 8; ++ks) {
            short8 b = *(const short8*)(fb + ks * 512);
            acc[i] = MFMA(aH[ks], b, acc[i]);
            acc[i] = MFMA(aL[ks], b, acc[i]);
        }
    }
    // bias + relu -> t into LDS
#pragma unroll
    for (int i = 0; i < 2; ++i) {
        int ctg = w * 2 + i, col = ctg * 16 + c;
        float u1b = ub1[col], cc = c2l[col];
#pragma unroll
        for (int reg = 0; reg < 4; ++reg) {
            int r16 = q * 4 + reg;
            float al = alpha[band + r16];
            float t = fmaxf(acc[i][reg] + u1b + al * cc, 0.f);
            u16 hi, lo;
            split2(t, hi, lo);
            int a = r16 * 128 + (((col >> 3) ^ r16) << 3) + (col & 7);
            tHi[a] = hi;
            tLo[a] = lo;
        }
    }
    __syncthreads();
    // ---- G2 ----
    short8 aH2[4], aL2[4];
#pragma unroll
    for (int ks = 0; ks < 4; ++ks) {
        int a = c * 128 + (((ks * 4 + q) ^ c) << 3);
        aH2[ks] = *(const short8*)&tHi[a];
        aL2[ks] = *(const short8*)&tLo[a];
    }
    f32x4 acc2[2] = {{0, 0, 0, 0}, {0, 0, 0, 0}};
#pragma unroll
    for (int i = 0; i < 2; ++i) {
        int ctg = w * 2 + i;
        const u16* fb = fG2 + (size_t)ctg * 4 * 512 + lane * 8;
#pragma unroll
        for (int ks = 0; ks < 4; ++ks) {
            short8 b = *(const short8*)(fb + ks * 512);
            acc2[i] = MFMA(aH2[ks], b, acc2[i]);
            acc2[i] = MFMA(aL2[ks], b, acc2[i]);
        }
    }
    // ---- residual + LN partials ----
    float vv[2][4];
#pragma unroll
    for (int i = 0; i < 2; ++i) {
        int ctg = w * 2 + i, col = ctg * 16 + c;
        float u2b = ub2[col];
#pragma unroll
        for (int reg = 0; reg < 4; ++reg) {
            size_t idx = (size_t)(band + q * 4 + reg) * HD + col;
            float hres = bf2f(h_hi[idx]) + bf2f(h_lo[idx]);
            vv[i][reg] = acc2[i][reg] + u2b + hres;
        }
    }
#pragma unroll
    for (int reg = 0; reg < 4; ++reg) {
        float s = vv[0][reg] + vv[1][reg];
        float s2 = vv[0][reg] * vv[0][reg] + vv[1][reg] * vv[1][reg];
        for (int m = 1; m < 16; m <<= 1) {
            s += __shfl_xor(s, m);
            s2 += __shfl_xor(s2, m);
        }
        if (c == 0) {
            red[q * 4 + reg][w][0] = s;
            red[q * 4 + reg][w][1] = s2;
        }
    }
    __syncthreads();  // also guarantees all t-reads (aH2) complete before h' overwrite
    float mu[4], rs[4];
#pragma unroll
    for (int reg = 0; reg < 4; ++reg) {
        int r16 = q * 4 + reg;
        float S1 = red[r16][0][0] + red[r16][1][0] + red[r16][2][0] + red[r16][3][0];
        float S2 = red[r16][0][1] + red[r16][1][1] + red[r16][2][1] + red[r16][3][1];
        float m = S1 * (1.f / HD);
        float var = S2 * (1.f / HD) - m * m;
        mu[reg] = m;
        rs[reg] = rsqrtf(var + LN_EPS);
    }
#pragma unroll
    for (int i = 0; i < 2; ++i) {
        int ctg = w * 2 + i, col = ctg * 16 + c;
        float gg = g[col], bv = bb[col];
#pragma unroll
        for (int reg = 0; reg < 4; ++reg) {
            int r16 = q * 4 + reg;
            float o = (vv[i][reg] - mu[reg]) * rs[reg] * gg + bv;
            u16 hi, lo;
            split2(o, hi, lo);
            int a = r16 * 128 + (((col >> 3) ^ r16) << 3) + (col & 7);
            tHi[a] = hi;
            tLo[a] = lo;
            if (!LAST) {
                size_t idx = (size_t)(band + r16) * HD + col;
                h_hi[idx] = hi;
                h_lo[idx] = lo;
            }
        }
    }
    __syncthreads();
    // ---- reload h' A-frags ----
    short8 aH3[4], aL3[4];
#pragma unroll
    for (int ks = 0; ks < 4; ++ks) {
        int a = c * 128 + (((ks * 4 + q) ^ c) << 3);
        aH3[ks] = *(const short8*)&tHi[a];
        aL3[ks] = *(const short8*)&tLo[a];
    }
    if (!LAST) {
        // PQ(next) = h' @ [W1a|W1b] (+ nb1 on P half)
#pragma unroll
        for (int i = 0; i < 4; ++i) {
            int ctg = w * 4 + i;
            const u16* fb = fPQ + (size_t)ctg * 4 * 512 + lane * 8;
            f32x4 a3 = {0, 0, 0, 0};
#pragma unroll
            for (int ks = 0; ks < 4; ++ks) {
                short8 b = *(const short8*)(fb + ks * 512);
                a3 = MFMA(aH3[ks], b, a3);
                a3 = MFMA(aL3[ks], b, a3);
            }
            int col = ctg * 16 + c;
            if (ctg < 8) {
                float bias = nb1[col];
#pragma unroll
                for (int reg = 0; reg < 4; ++reg)
                    PQf[(size_t)(band + q * 4 + reg) * HD + col] = a3[reg] + bias;
            } else {
                int colq = col - 128;
#pragma unroll
                for (int reg = 0; reg < 4; ++reg)
                    Qb[(size_t)(band + q * 4 + reg) * HD + colq] = f2bf(a3[reg]);
            }
        }
    } else {
        // decoder: out = relu(h'@dw1+db1)@dw2 + db2
        float part[4] = {0, 0, 0, 0};
#pragma unroll
        for (int i = 0; i < 2; ++i) {
            int ctg = w * 2 + i;
            const u16* fb = fDec + (size_t)ctg * 4 * 512 + lane * 8;
            f32x4 a3 = {0, 0, 0, 0};
#pragma unroll
            for (int ks = 0; ks < 4; ++ks) {
                short8 b = *(const short8*)(fb + ks * 512);
                a3 = MFMA(aH3[ks], b, a3);
                a3 = MFMA(aL3[ks], b, a3);
            }
            int col = ctg * 16 + c;
            float w2v = dw2[col], b1v = db1[col];
#pragma unroll
            for (int reg = 0; reg < 4; ++reg) part[reg] += fmaxf(a3[reg] + b1v, 0.f) * w2v;
        }
#pragma unroll
        for (int reg = 0; reg < 4; ++reg) {
            float s = part[reg];
            for (int m = 1; m < 16; m <<= 1) s += __shfl_xor(s, m);
            if (c == 0) red[q * 4 + reg][w][0] = s;
        }
        __syncthreads();
        if (tid < 16)
            out[band + tid] = red[tid][0][0] + red[tid][1][0] + red[tid][2][0] + red[tid][3][0] + db2[0];
    }
}

// ---------------- launch ----------------

extern "C" void kernel_launch(void* const* d_in, const int* in_sizes, int n_in,
                              void* d_out, int out_size, void* d_ws, size_t ws_size,
                              hipStream_t stream) {
    const float* x = (const float*)d_in[0];
    const int* eidx = (const int*)d_in[1];
    const float* eattr = (const float*)d_in[2];
    const float* enc_w1 = (const float*)d_in[3];
    const float* enc_b1 = (const float*)d_in[4];
    const float* enc_w2 = (const float*)d_in[5];
    const float* enc_b2 = (const float*)d_in[6];
    const float* msg_w1 = (const float*)d_in[7];
    const float* msg_b1 = (const float*)d_in[8];
    const float* msg_w2 = (const float*)d_in[9];
    const float* msg_b2 = (const float*)d_in[10];
    const float* upd_w1 = (const float*)d_in[11];
    const float* upd_b1 = (const float*)d_in[12];
    const float* upd_w2 = (const float*)d_in[13];
    const float* upd_b2 = (const float*)d_in[14];
    const float* ln_g = (const float*)d_in[15];
    const float* ln_b = (const float*)d_in[16];
    const float* dec_w1 = (const float*)d_in[17];
    const float* dec_b1 = (const float*)d_in[18];
    const float* dec_w2 = (const float*)d_in[19];
    const float* dec_b2 = (const float*)d_in[20];
    const int* srcp = eidx;
    const int* tgtp = eidx + NE;

    char* base = (char*)d_ws;
    size_t off = 0;
    auto alloc = [&](size_t bytes) -> void* {
        off = (off + 15) & ~(size_t)15;
        void* p = base + off;
        off += bytes;
        return p;
    };
    float4* sea = (float4*)alloc((size_t)NE * 16);
    float* PQf = (float*)alloc((size_t)NN * HD * 4);
    float* M2 = (float*)alloc((size_t)NL * HD * HD * 4);
    float* c2 = (float*)alloc((size_t)NL * HD * 4);
    float* inv = (float*)alloc((size_t)NN * 4);
    float* alpha = (float*)alloc((size_t)NN * 4);
    int* counts = (int*)alloc((size_t)NN * 4);
    int* offsets = (int*)alloc((size_t)(NN + 1) * 4);
    int* cursor = (int*)alloc((size_t)NN * 4);
    int* ssrc = (int*)alloc((size_t)NE * 4);
    u16* h_hi = (u16*)alloc((size_t)NN * HD * 2);
    u16* h_lo = (u16*)alloc((size_t)NN * HD * 2);
    u16* S_hi = (u16*)alloc((size_t)NN * HD * 2);
    u16* S_lo = (u16*)alloc((size_t)NN * HD * 2);
    u16* Qb = (u16*)alloc((size_t)NN * HD * 2);
    u16* fG1 = (u16*)alloc((size_t)131072 * 2);
    u16* fG2 = (u16*)alloc((size_t)65536 * 2);
    u16* fPQ = (u16*)alloc((size_t)131072 * 2);
    u16* fDec = (u16*)alloc((size_t)16384 * 2);
    u16* fEnc = (u16*)alloc((size_t)16384 * 2);

    k_zero<<<(NN + 255) / 256, 256, 0, stream>>>(counts);
    k_count<<<(NE + 255) / 256, 256, 0, stream>>>(tgtp, counts);
    k_scan<<<1, 1024, 0, stream>>>(counts, offsets, cursor, inv, alpha);
    k_scatter<<<(NE + 255) / 256, 256, 0, stream>>>(srcp, tgtp, eattr, cursor, ssrc, sea);
    k_prep<<<NL * 129 * HD / 256, 256, 0, stream>>>(msg_w2, msg_b2, upd_w1, M2, c2);
    k_frag<<<176, 256, 0, stream>>>(upd_w1, M2, upd_w2, msg_w1, dec_w1, enc_w2, fG1, fG2, fPQ, fDec, fEnc);
    k_enc<<<NN / 16, 256, 0, stream>>>(x, enc_w1, enc_b1, fEnc, enc_b2, fPQ, msg_b1, h_hi, h_lo, PQf, Qb);
    for (int l = 0; l < NL; ++l) {
        const float* wc = msg_w1 + (size_t)l * (2 * HD + EDIM) * HD + (size_t)2 * HD * HD;
        k_edge<<<NN / 4, 256, 0, stream>>>(PQf, Qb, offsets, ssrc, sea, wc, inv, S_hi, S_lo);
        if (l < NL - 1) {
            k_upd<false><<<NN / 16, 256, 0, stream>>>(
                h_hi, h_lo, S_hi, S_lo, fG1 + (size_t)l * 32768, fG2 + (size_t)l * 16384,
                fPQ + (size_t)(l + 1) * 32768, upd_b1 + l * HD, c2 + l * HD, upd_b2 + l * HD,
                ln_g + l * HD, ln_b + l * HD, alpha, msg_b1 + (size_t)(l + 1) * HD, PQf, Qb,
                nullptr, nullptr, nullptr, nullptr, nullptr);
        } else {
            k_upd<true><<<NN / 16, 256, 0, stream>>>(
                h_hi, h_lo, S_hi, S_lo, fG1 + (size_t)l * 32768, fG2 + (size_t)l * 16384,
                nullptr, upd_b1 + l * HD, c2 + l * HD, upd_b2 + l * HD,
                ln_g + l * HD, ln_b + l * HD, alpha, nullptr, nullptr, nullptr,
                fDec, dec_b1, dec_w2, dec_b2, (float*)d_out);
        }
    }
}